// Round 8
// baseline (389.901 us; speedup 1.0000x reference)
//
#include <hip/hip_runtime.h>
#include <stdint.h>

#define SEQ 4096
#define EMB 2048
#define NH 16
#define HDIM 128

typedef _Float16 f16;
typedef _Float16 f16x2 __attribute__((ext_vector_type(2)));
typedef _Float16 f16x4 __attribute__((ext_vector_type(4)));
typedef _Float16 f16x8 __attribute__((ext_vector_type(8)));
typedef float f32x4 __attribute__((ext_vector_type(4)));
typedef float f32x16 __attribute__((ext_vector_type(16)));
typedef unsigned u32x2 __attribute__((ext_vector_type(2)));

#define MFMA16(a, b, c) __builtin_amdgcn_mfma_f32_16x16x32_f16((a), (b), (c), 0, 0, 0)
#define MFMA32(a, b, c) __builtin_amdgcn_mfma_f32_32x32x16_f16((a), (b), (c), 0, 0, 0)

// workspace layout (f16 element offsets)
#define OFF_XH   0ull          // 4096x2048 x in fp16; later reused as AO (attention out)
#define OFF_WCAT 8388608ull    // [3072][2048] = Wq | Wk | Wv
#define OFF_WO   14680064ull   // Wo fp16 [2048][2048]
#define OFF_Q    23068672ull   // [4096][2048]  (pre-scaled by 1/sqrt(D)*log2e)
#define OFF_K    31457280ull   // [4096][512]
#define OFF_VT   33554432ull   // [512][4096]  (V transposed: Vt[hk*128+d][t])

__device__ __forceinline__ void gload16(const void* g, void* l) {
    __builtin_amdgcn_global_load_lds((const __attribute__((address_space(1))) unsigned int*)g,
                                     (__attribute__((address_space(3))) unsigned int*)l, 16, 0, 0);
}

// --- lane-pair swap (permlane on gfx950; shfl fallback keeps compile safe) ---
__device__ __forceinline__ void swap32p(uint32_t& x, uint32_t& y) {
#if __has_builtin(__builtin_amdgcn_permlane32_swap)
    u32x2 r = __builtin_amdgcn_permlane32_swap(x, y, false, false);
    x = r[0]; y = r[1];
#else
    int l = __lane_id();
    uint32_t xs = (uint32_t)__shfl_xor((int)x, 32, 64), ys = (uint32_t)__shfl_xor((int)y, 32, 64);
    uint32_t nx = (l < 32) ? x : ys;
    uint32_t ny = (l < 32) ? xs : y;
    x = nx; y = ny;
#endif
}

__device__ __forceinline__ uint32_t pk2(float a, float b) {
#if __has_builtin(__builtin_amdgcn_cvt_pkrtz)
    typedef __fp16 h16x2 __attribute__((ext_vector_type(2)));
    union { h16x2 h; uint32_t u; } z;
    z.h = __builtin_amdgcn_cvt_pkrtz(a, b);
    return z.u;
#else
    union { f16x2 h; uint32_t u; } z; z.h[0] = (f16)a; z.h[1] = (f16)b; return z.u;
#endif
}

// ---------------- fp32 -> fp16 conversion ----------------
__global__ __launch_bounds__(256) void cvt_kernel(
    const float* __restrict__ x, const float* __restrict__ wq,
    const float* __restrict__ wk, const float* __restrict__ wv,
    const float* __restrict__ wo, f16* __restrict__ ws)
{
    int g = blockIdx.x * 256 + threadIdx.x;
    const float* src;
    size_t dst;
    if (g < 2097152)      { src = x  + (size_t)g * 4;                 dst = OFF_XH + (size_t)g * 4; }
    else if (g < 3145728) { int r = g - 2097152; src = wq + (size_t)r * 4; dst = OFF_WCAT + (size_t)r * 4; }
    else if (g < 3407872) { int r = g - 3145728; src = wk + (size_t)r * 4; dst = OFF_WCAT + 4194304ull + (size_t)r * 4; }
    else if (g < 3670016) { int r = g - 3407872; src = wv + (size_t)r * 4; dst = OFF_WCAT + 5242880ull + (size_t)r * 4; }
    else                  { int r = g - 3670016; src = wo + (size_t)r * 4; dst = OFF_WO + (size_t)r * 4; }
    float4 v = *(const float4*)src;
    f16x4 hv;
    hv[0] = (f16)v.x; hv[1] = (f16)v.y; hv[2] = (f16)v.z; hv[3] = (f16)v.w;
    *(f16x4*)&ws[dst] = hv;
}

// ---------------- fused QKV projection GEMM ----------------
__global__ __launch_bounds__(256) void qkv_gemm(
    const f16* __restrict__ Xh, const f16* __restrict__ Wcat,
    f16* __restrict__ Qb, f16* __restrict__ Kb, f16* __restrict__ Vt)
{
    __shared__ f16 As[128 * 32];
    __shared__ f16 Bs[128 * 32];
    const int tid = threadIdx.x;
    const int lane = tid & 63;
    const int w = tid >> 6;
    const int llo = lane & 15, lhi = lane >> 4;
    const int m0 = blockIdx.y * 128;
    const int n0 = blockIdx.x * 128;
    const int wr = (w >> 1) * 64, wc = (w & 1) * 64;
    const float CS = 0.08838834764831845f * 1.4426950408889634f; // (1/sqrt(128))*log2(e)

    f32x4 acc[4][4] = {};

    for (int k0 = 0; k0 < EMB; k0 += 32) {
#pragma unroll
        for (int i = 0; i < 2; ++i) {
            int c = tid + 256 * i;
            gload16(Xh + (size_t)(m0 + (c >> 2)) * EMB + k0 + (c & 3) * 8, &As[c * 8]);
        }
#pragma unroll
        for (int i = 0; i < 2; ++i) {
            int c = tid + 256 * i;
            gload16(Wcat + (size_t)(n0 + (c >> 2)) * EMB + k0 + (c & 3) * 8, &Bs[c * 8]);
        }
        __syncthreads();
        f16x8 af[4], bf[4];
#pragma unroll
        for (int mi = 0; mi < 4; ++mi) af[mi] = *(const f16x8*)&As[(wr + mi * 16 + llo) * 32 + lhi * 8];
#pragma unroll
        for (int ni = 0; ni < 4; ++ni) bf[ni] = *(const f16x8*)&Bs[(wc + ni * 16 + llo) * 32 + lhi * 8];
#pragma unroll
        for (int mi = 0; mi < 4; ++mi)
#pragma unroll
            for (int ni = 0; ni < 4; ++ni)
                acc[mi][ni] = MFMA16(af[mi], bf[ni], acc[mi][ni]);
        __syncthreads();
    }

    if (n0 < 2048) {
        // Q output, pre-scaled by CS so attention skips the per-score multiply
#pragma unroll
        for (int mi = 0; mi < 4; ++mi) {
            int m = m0 + wr + mi * 16 + lhi * 4;
#pragma unroll
            for (int ni = 0; ni < 4; ++ni) {
                int n = n0 + wc + ni * 16 + llo;
#pragma unroll
                for (int r = 0; r < 4; ++r)
                    Qb[(size_t)(m + r) * EMB + n] = (f16)(acc[mi][ni][r] * CS);
            }
        }
    } else if (n0 < 2560) {
#pragma unroll
        for (int mi = 0; mi < 4; ++mi) {
            int m = m0 + wr + mi * 16 + lhi * 4;
#pragma unroll
            for (int ni = 0; ni < 4; ++ni) {
                int n = n0 + wc + ni * 16 + llo - 2048;
#pragma unroll
                for (int r = 0; r < 4; ++r)
                    Kb[(size_t)(m + r) * 512 + n] = (f16)acc[mi][ni][r];
            }
        }
    } else {
#pragma unroll
        for (int mi = 0; mi < 4; ++mi) {
            int mb = m0 + wr + mi * 16 + lhi * 4;
#pragma unroll
            for (int ni = 0; ni < 4; ++ni) {
                int n = n0 + wc + ni * 16 + llo - 2560;
                f16x4 pv;
#pragma unroll
                for (int r = 0; r < 4; ++r) pv[r] = (f16)acc[mi][ni][r];
                *(f16x4*)&Vt[(size_t)n * SEQ + mb] = pv;
            }
        }
    }
}

// ---------------- flash attention (GQA), 4 waves x 32 q-rows, 32x32x16 MFMA ----------------
// LDS geometry (both 64 rows x 128 f16 = 256 B rows, 16-slot XOR swizzle):
//   Ks: row = t (0..63); 16B chunk at (row, slot) holds K[t0+row][dchunk = slot ^ (row&15)]
//   Vs: row = d>>1;      chunk at (row, slot): logical = slot^(row&15), d = 2*row + (logical>>3),
//                        tchunk = logical&7 -> holds Vt[d][t0 + tchunk*8]
__global__ __launch_bounds__(256, 2) void attn_kernel(
    const f16* __restrict__ Qb, const f16* __restrict__ Kb, const f16* __restrict__ Vt,
    f16* __restrict__ AO)
{
    __shared__ f16 Ks[2][64 * 128];
    __shared__ f16 Vs[2][64 * 128];
    const int tid = threadIdx.x, lane = tid & 63, w = tid >> 6;
    const int l31 = lane & 31, hi = lane >> 5;
    const int h = blockIdx.y, hk = h >> 2;
    const int wm0 = blockIdx.x * 128 + w * 32;   // this wave's 32 q-rows
    const int hcol = h * HDIM;
    const int t15 = l31 & 15;
    const int vrow15 = l31 >> 1;                 // (d>>1)&15 for PV reads

    // Q fragments: B-operand of swapped QK^T: col m=l31, k-chunk kk: k = kk*16 + hi*8 + j
    f16x8 qf[8];
#pragma unroll
    for (int kk = 0; kk < 8; ++kk)
        qf[kk] = *(const f16x8*)&Qb[(size_t)(wm0 + l31) * EMB + hcol + kk * 16 + hi * 8];

    // hoisted staging source pointers (advance by uniform t0 per tile)
    const f16* kgp[4];
    const f16* vgp[4];
#pragma unroll
    for (int i = 0; i < 4; ++i) {
        int c = tid + 256 * i;
        int row = c >> 4, slot = c & 15;
        int dch = slot ^ (row & 15);
        kgp[i] = Kb + (size_t)row * 512 + hk * HDIM + dch * 8;
        int lg = slot ^ (row & 15);
        int d = 2 * row + (lg >> 3), tc = lg & 7;
        vgp[i] = Vt + (size_t)(hk * HDIM + d) * SEQ + tc * 8;
    }

    float mrun = -3.0e38f;
    float lsum = 0.f;        // per-lane partial row-sum (row m = l31); combined at the end
    f32x16 acc[4] = {};      // 4 d-tiles of 32 cols each

    auto stage = [&](int buf, int t0) {
#pragma unroll
        for (int i = 0; i < 4; ++i)
            gload16(kgp[i] + (size_t)t0 * 512, &Ks[buf][(tid + 256 * i) * 8]);
#pragma unroll
        for (int i = 0; i < 4; ++i)
            gload16(vgp[i] + t0, &Vs[buf][(tid + 256 * i) * 8]);
    };

    stage(0, 0);
    __syncthreads();

    for (int tt = 0; tt < 64; ++tt) {
        int cur = tt & 1;
        if (tt < 63) stage(cur ^ 1, (tt + 1) * 64);  // prefetch overlaps compute

        // QK^T swapped: S^T = K_tile x Q -> lane holds col m=l31; rows t reg-mapped
        f32x16 st0 = {}, st1 = {};
        __builtin_amdgcn_s_setprio(1);
#pragma unroll
        for (int kk = 0; kk < 8; ++kk) {
            int slot = (kk * 2 + hi) ^ t15;
            f16x8 kf0 = *(const f16x8*)&Ks[cur][l31 * 128 + slot * 8];
            f16x8 kf1 = *(const f16x8*)&Ks[cur][(32 + l31) * 128 + slot * 8];
            st0 = MFMA32(kf0, qf[kk], st0);
            st1 = MFMA32(kf1, qf[kk], st1);
        }
        __builtin_amdgcn_s_setprio(0);

        // tile max: all 32 scores of row m=l31 are local (split across hi halves)
        float mx[8];
#pragma unroll
        for (int i = 0; i < 8; ++i)
            mx[i] = fmaxf(fmaxf(st0[i], st0[i + 8]), fmaxf(st1[i], st1[i + 8]));
#pragma unroll
        for (int i = 0; i < 4; ++i) mx[i] = fmaxf(mx[i], mx[i + 4]);
        float tmax = fmaxf(fmaxf(mx[0], mx[1]), fmaxf(mx[2], mx[3]));
        {
            uint32_t a = __float_as_uint(tmax), b = a;
            swap32p(a, b);
            tmax = fmaxf(__uint_as_float(a), __uint_as_float(b));
        }

        // defer-max (T13): only rescale when the max grew by > 8 (log2 domain)
        if (__any(tmax > mrun + 8.f)) {
            float mnew = fmaxf(mrun, tmax);
            float alpha = __builtin_amdgcn_exp2f(mrun - mnew);
            mrun = mnew; lsum *= alpha;
            float ar[16];
#pragma unroll
            for (int r = 0; r < 16; ++r)
                ar[r] = __shfl(alpha, (r & 3) + 8 * (r >> 2) + 4 * hi, 64);
#pragma unroll
            for (int dt = 0; dt < 4; ++dt)
#pragma unroll
                for (int r = 0; r < 16; ++r) acc[dt][r] *= ar[r];
        }

        // exp (P bounded by 2^8), per-lane partial sum
        float ts = 0.f;
#pragma unroll
        for (int r = 0; r < 16; ++r) { float p = __builtin_amdgcn_exp2f(st0[r] - mrun); st0[r] = p; ts += p; }
#pragma unroll
        for (int r = 0; r < 16; ++r) { float p = __builtin_amdgcn_exp2f(st1[r] - mrun); st1[r] = p; ts += p; }
        lsum += ts;

        // pack P to fp16 A-frags: kt-chunk of t=16; per kt: 4 cvt_pk + 2 permlane32_swap
        f16x8 pa[4];
#define PACKHALF(SRC, PH, KT)                                                   \
        {                                                                       \
            uint32_t X0 = pk2(SRC[(PH)*8 + 0], SRC[(PH)*8 + 1]);                \
            uint32_t X1 = pk2(SRC[(PH)*8 + 2], SRC[(PH)*8 + 3]);                \
            uint32_t X2 = pk2(SRC[(PH)*8 + 4], SRC[(PH)*8 + 5]);                \
            uint32_t X3 = pk2(SRC[(PH)*8 + 6], SRC[(PH)*8 + 7]);                \
            swap32p(X0, X2); swap32p(X1, X3);                                   \
            union { f16x8 v; uint32_t u[4]; } pu;                               \
            pu.u[0] = X0; pu.u[1] = X1; pu.u[2] = X2; pu.u[3] = X3;             \
            pa[KT] = pu.v;                                                      \
        }
        PACKHALF(st0, 0, 0)
        PACKHALF(st0, 1, 1)
        PACKHALF(st1, 0, 2)
        PACKHALF(st1, 1, 3)
#undef PACKHALF

        // PV: out[m][d] += P * V ; B-frag: col d = dt*32+l31, k = t = kt*16 + hi*8 + j
        __builtin_amdgcn_s_setprio(1);
#pragma unroll
        for (int dt = 0; dt < 4; ++dt) {
            int row = dt * 16 + vrow15;
#pragma unroll
            for (int kt = 0; kt < 4; ++kt) {
                int slot = ((l31 & 1) * 8 + kt * 2 + hi) ^ vrow15;
                f16x8 vf = *(const f16x8*)&Vs[cur][row * 128 + slot * 8];
                acc[dt] = MFMA32(pa[kt], vf, acc[dt]);
            }
        }
        __builtin_amdgcn_s_setprio(0);

        __syncthreads();  // drains prefetch (vmcnt 0) + barrier: next buffer ready
    }

    // finalize: combine row-sum halves, divide, store merged-head fp16 [4096][2048]
    {
        uint32_t a = __float_as_uint(lsum), b = a;
        swap32p(a, b);
        lsum = __uint_as_float(a) + __uint_as_float(b);
    }
    float linv = 1.0f / lsum;
    float lr[16];
#pragma unroll
    for (int r = 0; r < 16; ++r)
        lr[r] = __shfl(linv, (r & 3) + 8 * (r >> 2) + 4 * hi, 64);
#pragma unroll
    for (int dt = 0; dt < 4; ++dt)
#pragma unroll
        for (int r = 0; r < 16; ++r) {
            int m = (r & 3) + 8 * (r >> 2) + 4 * hi;
            AO[(size_t)(wm0 + m) * EMB + hcol + dt * 32 + l31] = (f16)(acc[dt][r] * lr[r]);
        }
}

// ---------------- output projection: out = AO @ Wo^T, fp32 out ----------------
__global__ __launch_bounds__(256) void o_gemm(
    const f16* __restrict__ A, const f16* __restrict__ Bw,
    float* __restrict__ Co)
{
    __shared__ f16 As[128 * 32];
    __shared__ f16 Bs[128 * 32];
    const int tid = threadIdx.x;
    const int lane = tid & 63;
    const int w = tid >> 6;
    const int llo = lane & 15, lhi = lane >> 4;
    const int m0 = blockIdx.y * 128;
    const int n0 = blockIdx.x * 128;
    const int wr = (w >> 1) * 64, wc = (w & 1) * 64;

    f32x4 acc[4][4] = {};

    for (int k0 = 0; k0 < EMB; k0 += 32) {
#pragma unroll
        for (int i = 0; i < 2; ++i) {
            int c = tid + 256 * i;
            gload16(A + (size_t)(m0 + (c >> 2)) * EMB + k0 + (c & 3) * 8, &As[c * 8]);
        }
#pragma unroll
        for (int i = 0; i < 2; ++i) {
            int c = tid + 256 * i;
            gload16(Bw + (size_t)(n0 + (c >> 2)) * EMB + k0 + (c & 3) * 8, &Bs[c * 8]);
        }
        __syncthreads();
        f16x8 af[4], bf[4];
#pragma unroll
        for (int mi = 0; mi < 4; ++mi) af[mi] = *(const f16x8*)&As[(wr + mi * 16 + llo) * 32 + lhi * 8];
#pragma unroll
        for (int ni = 0; ni < 4; ++ni) bf[ni] = *(const f16x8*)&Bs[(wc + ni * 16 + llo) * 32 + lhi * 8];
#pragma unroll
        for (int mi = 0; mi < 4; ++mi)
#pragma unroll
            for (int ni = 0; ni < 4; ++ni)
                acc[mi][ni] = MFMA16(af[mi], bf[ni], acc[mi][ni]);
        __syncthreads();
    }

#pragma unroll
    for (int mi = 0; mi < 4; ++mi) {
        int m = m0 + wr + mi * 16 + lhi * 4;
#pragma unroll
        for (int ni = 0; ni < 4; ++ni) {
            int n = n0 + wc + ni * 16 + llo;
#pragma unroll
            for (int r = 0; r < 4; ++r)
                Co[(size_t)(m + r) * EMB + n] = acc[mi][ni][r];
        }
    }
}

extern "C" void kernel_launch(void* const* d_in, const int* in_sizes, int n_in,
                              void* d_out, int out_size, void* d_ws, size_t ws_size,
                              hipStream_t stream) {
    const float* x  = (const float*)d_in[0];
    const float* wq = (const float*)d_in[1];
    const float* wk = (const float*)d_in[2];
    const float* wv = (const float*)d_in[3];
    const float* wo = (const float*)d_in[4];
    f16* ws = (f16*)d_ws;

    f16* Xh   = ws + OFF_XH;     // also AO after attention
    f16* Wcat = ws + OFF_WCAT;
    f16* Wo16 = ws + OFF_WO;
    f16* Qb   = ws + OFF_Q;
    f16* Kb   = ws + OFF_K;
    f16* Vt   = ws + OFF_VT;

    cvt_kernel<<<18432, 256, 0, stream>>>(x, wq, wk, wv, wo, ws);
    qkv_gemm<<<dim3(24, 32), 256, 0, stream>>>(Xh, Wcat, Qb, Kb, Vt);
    attn_kernel<<<dim3(32, 16), 256, 0, stream>>>(Qb, Kb, Vt, Xh /*AO*/);
    o_gemm<<<dim3(16, 32), 256, 0, stream>>>(Xh /*AO*/, Wo16, (float*)d_out);
}